// Round 5
// baseline (149.114 us; speedup 1.0000x reference)
//
#include <hip/hip_runtime.h>

// CanadarmJacob: 131072 independent items.
// R2/R4 evidence: kernel <45.5us; com/out coalescing was NEUTRAL -> pose
// gather (21x float4/thread at 576B stride, 64 lines/instr) is the last
// scattered path. R5: block-coalesced pose copy -> compacted LDS.
//  - copy offs 0..27 (first 7 lines/item; lines 7,8 dead -> fetch unchanged)
//  - LDS stride 23 float4/item (92 dwords == 28 mod 32 -> 2-way, free)
//  - com direct scalar (proven neutral), out staged via LDS (as R4)

#define BLK 128
#define IT_F4 23   // padded LDS float4 stride per item

__global__ __launch_bounds__(BLK) void canadarm_jacob_kernel(
    const float* __restrict__ com,
    const float* __restrict__ pose,
    const int* __restrict__ bm_ptr,
    float* __restrict__ out,
    int n_items)
{
    __shared__ float4 lds4[BLK * IT_F4];   // 47104 B; reused for out staging

    const int tid = threadIdx.x;
    const int item0 = blockIdx.x * BLK;    // n_items % BLK == 0 (131072/128)

    // ---- compile-time constants (match reference f32 values) ----
    const float MASS[7] = {105.98f, 105.98f, 314.98f, 279.2f, 105.98f, 105.98f, 243.66f};
    const float SUMM[7] = {1261.76f, 1155.78f, 1049.80f, 734.82f, 455.62f, 349.64f, 243.66f};
    const float SIX[7] = {79.083f, 66.893f, 54.703f, 39.293f, 29.771f, 21.466f, 9.336f};
    const float SIY[7] = {4144.971f, 4132.781f, 4120.591f, 2025.881f, 59.601f, 56.540f, 44.410f};
    const float SIZ[7] = {4131.1016f, 4128.0406f, 4124.9796f, 2021.7896f, 55.5096f, 47.471f, 44.410f};
    const float TM     = 101505.42f;
    const float INV_TM = 1.0f / 101505.42f;
    const float BCZ    = 6.65f * 243.66f / 100243.66f;

    // ---- stage pose coalesced: offs 0..27 of each of 128 items ----
    // live offs per row r(0..2): 9r+{0,1,4,5,6,7,8} -> slot 7r+{0,1,2,3,4,5,6}
    {
        const float4* Pb = reinterpret_cast<const float4*>(pose) + (size_t)item0 * 36;
#pragma unroll
        for (int it = 0; it < 28; ++it) {
            const int c = it * BLK + tid;        // 0..3583
            const int item = c / 28;
            const int off = c - item * 28;       // 0..27
            const float4 v = Pb[item * 36 + off];
            const int r = off / 9;               // 3 only for off==27
            const int oo = off - r * 9;          // 0..8
            const bool live = (r < 3) && (oo < 2 || oo >= 4);
            const int slot = 7 * r + (oo < 2 ? oo : oo - 2);
            if (live) lds4[item * IT_F4 + slot] = v;
        }
    }
    __syncthreads();

    // ---- extract rot/tr from LDS (2-way bank alias, free) ----
    const float4* L = &lds4[tid * IT_F4];
    float rot[3][7];
    float tr[3][8];
#pragma unroll
    for (int r = 0; r < 3; ++r) {
        const float4 q0 = L[7 * r + 0];
        const float4 q1 = L[7 * r + 1];
        const float4 q4 = L[7 * r + 2];
        const float4 q5 = L[7 * r + 3];
        const float4 q6 = L[7 * r + 4];
        const float4 q7 = L[7 * r + 5];
        const float4 q8 = L[7 * r + 6];
        rot[r][0] = q4.z;
        rot[r][1] = q0.y;
        rot[r][2] = q5.x;
        rot[r][3] = q5.y;
        rot[r][4] = -q5.z;   // ROT_SIGN[4] = -1
        rot[r][5] = q1.y;
        rot[r][6] = q6.x;
        tr[r][0] = q6.w;
        tr[r][1] = q7.x; tr[r][2] = q7.y; tr[r][3] = q7.z; tr[r][4] = q7.w;
        tr[r][5] = q8.x; tr[r][6] = q8.y; tr[r][7] = q8.z;
    }

    const int bm = bm_ptr[0];
    float o[42];

    if (bm) {
        // ---- com: direct per-thread loads (measured neutral vs staged) ----
        const float* C = com + (size_t)(item0 + tid) * 21;
        float cm[3][7];
#pragma unroll
        for (int r = 0; r < 3; ++r)
#pragma unroll
            for (int i = 0; i < 7; ++i) cm[r][i] = C[r * 7 + i];

        float scx = 0.f, scy = 0.f, scz = 0.f;
#pragma unroll
        for (int i = 0; i < 7; ++i) {
            scx += cm[0][i] * MASS[i];
            scy += cm[1][i] * MASS[i];
            scz += cm[2][i] * MASS[i];
        }
        const float vx = scx * INV_TM;
        const float vy = scy * INV_TM;
        const float vz = scz * INV_TM - BCZ;

        float dp[3][7], jt[3][7];
        float hxx = SIX[0], hyy = SIY[0], hzz = SIZ[0];
        float hxy = 0.f, hxz = 0.f, hyz = 0.f;
#pragma unroll
        for (int i = 0; i < 7; ++i) {
            const float x = cm[0][i] - tr[0][i];
            const float y = cm[1][i] - tr[1][i];
            const float z = cm[2][i] - tr[2][i];
            dp[0][i] = x; dp[1][i] = y; dp[2][i] = z;
            jt[0][i] = rot[1][i] * z - rot[2][i] * y;
            jt[1][i] = rot[2][i] * x - rot[0][i] * z;
            jt[2][i] = rot[0][i] * y - rot[1][i] * x;
            const float m = MASS[i];
            hxx += m * (y * y + z * z);
            hyy += m * (x * x + z * z);
            hzz += m * (x * x + y * y);
            hxy -= m * x * y;
            hxz -= m * x * z;
            hyz -= m * y * z;
        }

        float wx[7], wy[7], wz[7];
        wx[6] = MASS[6] * dp[0][6];
        wy[6] = MASS[6] * dp[1][6];
        wz[6] = MASS[6] * dp[2][6];
#pragma unroll
        for (int k = 5; k >= 0; --k) {
            wx[k] = wx[k + 1] + MASS[k] * dp[0][k];
            wy[k] = wy[k + 1] + MASS[k] * dp[1][k];
            wz[k] = wz[k + 1] + MASS[k] * dp[2][k];
        }

        const float vv = vx * vx + vy * vy + vz * vz;
        const float a  = hxx + TM * (vx * vx - vv);
        const float b  = hxy + TM * (vx * vy);
        const float c  = hxz + TM * (vx * vz);
        const float e  = hyy + TM * (vy * vy - vv);
        const float f  = hyz + TM * (vy * vz);
        const float i9 = hzz + TM * (vz * vz - vv);

        const float c11 = e * i9 - f * f;
        const float c12 = c * f - b * i9;
        const float c13 = b * f - e * c;
        const float det = a * c11 + b * c12 + c * c13;
        const float rdet = 1.0f / det;
        const float i00 = c11 * rdet;
        const float i01 = c12 * rdet;
        const float i02 = c13 * rdet;
        const float i11 = (a * i9 - c * c) * rdet;
        const float i12 = (c * b - a * f) * rdet;
        const float i22 = (a * e - b * b) * rdet;

#pragma unroll
        for (int k = 0; k < 7; ++k) {
            const float ux = wx[k] - SUMM[k] * vx;
            const float uy = wy[k] - SUMM[k] * vy;
            const float uz = wz[k] - SUMM[k] * vz;
            const float jx = jt[0][k], jy = jt[1][k], jz = jt[2][k];
            const float htx = SIX[k] * rot[0][k] + uy * jz - uz * jy;
            const float hty = SIY[k] * rot[1][k] + uz * jx - ux * jz;
            const float htz = SIZ[k] * rot[2][k] + ux * jy - uy * jx;
            const float bx = i00 * htx + i01 * hty + i02 * htz;
            const float by = i01 * htx + i11 * hty + i12 * htz;
            const float bz = i02 * htx + i12 * hty + i22 * htz;
            const float s = SUMM[k] * INV_TM;
            o[0 * 7 + k] = -(s * jx + vy * bz - vz * by);
            o[1 * 7 + k] = -(s * jy + vz * bx - vx * bz);
            o[2 * 7 + k] = -(s * jz + vx * by - vy * bx);
            o[3 * 7 + k] = -bx;
            o[4 * 7 + k] = -by;
            o[5 * 7 + k] = -bz;
        }
    } else {
#pragma unroll
        for (int k = 0; k < 7; ++k) {
            const float dx = tr[0][7] - tr[0][k];
            const float dy = tr[1][7] - tr[1][k];
            const float dz = tr[2][7] - tr[2][k];
            o[0 * 7 + k] = rot[1][k] * dz - rot[2][k] * dy;
            o[1 * 7 + k] = rot[2][k] * dx - rot[0][k] * dz;
            o[2 * 7 + k] = rot[0][k] * dy - rot[1][k] * dx;
            o[3 * 7 + k] = rot[0][k];
            o[4 * 7 + k] = rot[1][k];
            o[5 * 7 + k] = rot[2][k];
        }
    }

    // ---- stage output in LDS (reuse), stream out coalesced float4 ----
    __syncthreads();   // pose reads done; safe to overwrite LDS
    float* ldsf = reinterpret_cast<float*>(lds4);
#pragma unroll
    for (int j = 0; j < 42; ++j) ldsf[tid * 42 + j] = o[j];  // BLK*42=5376 floats = 21504B, fits
    __syncthreads();

    // block out region: BLK*42 floats = 1344 float4 (base = blockIdx*21504B, 16-aligned)
    {
        float4* Ob4 = reinterpret_cast<float4*>(out) + (size_t)blockIdx.x * (BLK * 42 / 4);
        const float4* Lf4 = reinterpret_cast<const float4*>(ldsf);
#pragma unroll
        for (int i = 0; i < 10; ++i) Ob4[tid + i * BLK] = Lf4[tid + i * BLK];
        if (tid < BLK * 42 / 4 - 10 * BLK)   // 1344 - 1280 = 64
            Ob4[tid + 10 * BLK] = Lf4[tid + 10 * BLK];
    }
}

extern "C" void kernel_launch(void* const* d_in, const int* in_sizes, int n_in,
                              void* d_out, int out_size, void* d_ws, size_t ws_size,
                              hipStream_t stream) {
    const float* com  = (const float*)d_in[0];   // (512,256,3,7)  f32
    const float* pose = (const float*)d_in[1];   // (512,256,4,4,9) f32
    const int*   bm   = (const int*)d_in[2];     // scalar
    float* out = (float*)d_out;                  // (512,256,6,7)  f32

    const int n_items = in_sizes[0] / 21;        // 131072 (divisible by BLK)
    const int grid = n_items / BLK;              // 1024
    canadarm_jacob_kernel<<<grid, BLK, 0, stream>>>(com, pose, bm, out, n_items);
}

// Round 6
// 124.351 us; speedup vs baseline: 1.1991x; 1.1991x over previous
//
#include <hip/hip_runtime.h>

// CanadarmJacob: 131072 independent items.
// R5 counters: kernel 54.9us, 14% HBM BW, VALUBusy 7%, Occ 9.8% -> latency-
// bound: per-wave load serialization (~900cyc x ~28 loads = 25K cyc/wave).
// R6: global_load_lds async DMA staging (guaranteed MLP, no VGPR dep):
//  - BLK=64 (1 wave/block), 2048 blocks, __launch_bounds__(64,1)
//  - pose: 21 live float4/item -> LDS (21504B), consume stride 21 f4
//    ((5l)%8 covers all bank groups -> conflict-free, no swizzle)
//  - com: identity f4 copy (336 f4 + clamp tail), consume stride 21 dwords
//  - ONE vmcnt(0)+barrier; compute unchanged (verified absmax 0.0078)

#define BLK 64

typedef const __attribute__((address_space(1))) void GAS;
typedef __attribute__((address_space(3))) void LAS;

__global__ __launch_bounds__(BLK, 1) void canadarm_jacob_kernel(
    const float* __restrict__ com,
    const float* __restrict__ pose,
    const int* __restrict__ bm_ptr,
    float* __restrict__ out)
{
    __shared__ float4 pose_lds[BLK * 21];   // 21504 B (reused for out staging)
    __shared__ float4 com_lds[384];         // 6144 B (336 used + tail pad)

    const int tid = threadIdx.x;            // == lane (1 wave/block)
    const int item0 = blockIdx.x * BLK;

    // ---- constants ----
    const float MASS[7] = {105.98f, 105.98f, 314.98f, 279.2f, 105.98f, 105.98f, 243.66f};
    const float SUMM[7] = {1261.76f, 1155.78f, 1049.80f, 734.82f, 455.62f, 349.64f, 243.66f};
    const float SIX[7] = {79.083f, 66.893f, 54.703f, 39.293f, 29.771f, 21.466f, 9.336f};
    const float SIY[7] = {4144.971f, 4132.781f, 4120.591f, 2025.881f, 59.601f, 56.540f, 44.410f};
    const float SIZ[7] = {4131.1016f, 4128.0406f, 4124.9796f, 2021.7896f, 55.5096f, 47.471f, 44.410f};
    const float TM     = 101505.42f;
    const float INV_TM = 1.0f / 101505.42f;
    const float BCZ    = 6.65f * 243.66f / 100243.66f;

    // ---- async DMA staging: pose live-f4 compaction ----
    // logical LDS slot d = item*21 + (7r+s); source f4 = item*36 + 9r + off(s)
    // off(s) = s<2 ? s : s+2   (live offs {0,1,4,5,6,7,8} per row)
    {
        const float4* Pb4 = reinterpret_cast<const float4*>(pose) + (size_t)item0 * 36;
#pragma unroll
        for (int i = 0; i < 21; ++i) {
            const int d    = i * BLK + tid;      // 0..1343
            const int item = d / 21;
            const int li   = d - item * 21;      // 0..20
            const int r    = li / 7;
            const int q    = li - r * 7;         // 0..6
            const int off  = 9 * r + (q < 2 ? q : q + 2);
            __builtin_amdgcn_global_load_lds(
                (GAS*)(Pb4 + item * 36 + off),
                (LAS*)(pose_lds + i * BLK), 16, 0, 0);
        }
        // com: identity f4 copy, 336 f4 per block (clamp tail sources)
        const float4* Cb4 = reinterpret_cast<const float4*>(com) + (size_t)item0 * 21 / 4 * 4 / 4;
        // item0*21 floats = item0*84 bytes; item0 multiple of 64 -> /4 exact:
        const float4* Cb4x = reinterpret_cast<const float4*>(com + (size_t)item0 * 21);
#pragma unroll
        for (int i = 0; i < 6; ++i) {
            const int d  = i * BLK + tid;        // 0..383
            const int dc = d < 336 ? d : 335;    // clamp source in-bounds
            __builtin_amdgcn_global_load_lds(
                (GAS*)(Cb4x + dc),
                (LAS*)(com_lds + i * BLK), 16, 0, 0);
        }
        (void)Cb4;
    }
    asm volatile("s_waitcnt vmcnt(0)" ::: "memory");
    __syncthreads();

    // ---- extract rot/tr from LDS (stride 21 f4 -> conflict-free) ----
    const float4* L = &pose_lds[tid * 21];
    float rot[3][7];
    float tr[3][8];
#pragma unroll
    for (int r = 0; r < 3; ++r) {
        const float4 q0 = L[7 * r + 0];
        const float4 q1 = L[7 * r + 1];
        const float4 q4 = L[7 * r + 2];
        const float4 q5 = L[7 * r + 3];
        const float4 q6 = L[7 * r + 4];
        const float4 q7 = L[7 * r + 5];
        const float4 q8 = L[7 * r + 6];
        rot[r][0] = q4.z;
        rot[r][1] = q0.y;
        rot[r][2] = q5.x;
        rot[r][3] = q5.y;
        rot[r][4] = -q5.z;   // ROT_SIGN[4] = -1
        rot[r][5] = q1.y;
        rot[r][6] = q6.x;
        tr[r][0] = q6.w;
        tr[r][1] = q7.x; tr[r][2] = q7.y; tr[r][3] = q7.z; tr[r][4] = q7.w;
        tr[r][5] = q8.x; tr[r][6] = q8.y; tr[r][7] = q8.z;
    }

    const int bm = bm_ptr[0];
    float o[42];

    if (bm) {
        // ---- com from LDS: stride-21 dwords (odd -> 2-way alias, free) ----
        const float* Cf = reinterpret_cast<const float*>(com_lds) + tid * 21;
        float cm[3][7];
#pragma unroll
        for (int r = 0; r < 3; ++r)
#pragma unroll
            for (int i = 0; i < 7; ++i) cm[r][i] = Cf[r * 7 + i];

        float scx = 0.f, scy = 0.f, scz = 0.f;
#pragma unroll
        for (int i = 0; i < 7; ++i) {
            scx += cm[0][i] * MASS[i];
            scy += cm[1][i] * MASS[i];
            scz += cm[2][i] * MASS[i];
        }
        const float vx = scx * INV_TM;
        const float vy = scy * INV_TM;
        const float vz = scz * INV_TM - BCZ;

        float dp[3][7], jt[3][7];
        float hxx = SIX[0], hyy = SIY[0], hzz = SIZ[0];
        float hxy = 0.f, hxz = 0.f, hyz = 0.f;
#pragma unroll
        for (int i = 0; i < 7; ++i) {
            const float x = cm[0][i] - tr[0][i];
            const float y = cm[1][i] - tr[1][i];
            const float z = cm[2][i] - tr[2][i];
            dp[0][i] = x; dp[1][i] = y; dp[2][i] = z;
            jt[0][i] = rot[1][i] * z - rot[2][i] * y;
            jt[1][i] = rot[2][i] * x - rot[0][i] * z;
            jt[2][i] = rot[0][i] * y - rot[1][i] * x;
            const float m = MASS[i];
            hxx += m * (y * y + z * z);
            hyy += m * (x * x + z * z);
            hzz += m * (x * x + y * y);
            hxy -= m * x * y;
            hxz -= m * x * z;
            hyz -= m * y * z;
        }

        float wx[7], wy[7], wz[7];
        wx[6] = MASS[6] * dp[0][6];
        wy[6] = MASS[6] * dp[1][6];
        wz[6] = MASS[6] * dp[2][6];
#pragma unroll
        for (int k = 5; k >= 0; --k) {
            wx[k] = wx[k + 1] + MASS[k] * dp[0][k];
            wy[k] = wy[k + 1] + MASS[k] * dp[1][k];
            wz[k] = wz[k + 1] + MASS[k] * dp[2][k];
        }

        const float vv = vx * vx + vy * vy + vz * vz;
        const float a  = hxx + TM * (vx * vx - vv);
        const float b  = hxy + TM * (vx * vy);
        const float c  = hxz + TM * (vx * vz);
        const float e  = hyy + TM * (vy * vy - vv);
        const float f  = hyz + TM * (vy * vz);
        const float i9 = hzz + TM * (vz * vz - vv);

        const float c11 = e * i9 - f * f;
        const float c12 = c * f - b * i9;
        const float c13 = b * f - e * c;
        const float det = a * c11 + b * c12 + c * c13;
        const float rdet = 1.0f / det;
        const float i00 = c11 * rdet;
        const float i01 = c12 * rdet;
        const float i02 = c13 * rdet;
        const float i11 = (a * i9 - c * c) * rdet;
        const float i12 = (c * b - a * f) * rdet;
        const float i22 = (a * e - b * b) * rdet;

#pragma unroll
        for (int k = 0; k < 7; ++k) {
            const float ux = wx[k] - SUMM[k] * vx;
            const float uy = wy[k] - SUMM[k] * vy;
            const float uz = wz[k] - SUMM[k] * vz;
            const float jx = jt[0][k], jy = jt[1][k], jz = jt[2][k];
            const float htx = SIX[k] * rot[0][k] + uy * jz - uz * jy;
            const float hty = SIY[k] * rot[1][k] + uz * jx - ux * jz;
            const float htz = SIZ[k] * rot[2][k] + ux * jy - uy * jx;
            const float bx = i00 * htx + i01 * hty + i02 * htz;
            const float by = i01 * htx + i11 * hty + i12 * htz;
            const float bz = i02 * htx + i12 * hty + i22 * htz;
            const float s = SUMM[k] * INV_TM;
            o[0 * 7 + k] = -(s * jx + vy * bz - vz * by);
            o[1 * 7 + k] = -(s * jy + vz * bx - vx * bz);
            o[2 * 7 + k] = -(s * jz + vx * by - vy * bx);
            o[3 * 7 + k] = -bx;
            o[4 * 7 + k] = -by;
            o[5 * 7 + k] = -bz;
        }
    } else {
#pragma unroll
        for (int k = 0; k < 7; ++k) {
            const float dx = tr[0][7] - tr[0][k];
            const float dy = tr[1][7] - tr[1][k];
            const float dz = tr[2][7] - tr[2][k];
            o[0 * 7 + k] = rot[1][k] * dz - rot[2][k] * dy;
            o[1 * 7 + k] = rot[2][k] * dx - rot[0][k] * dz;
            o[2 * 7 + k] = rot[0][k] * dy - rot[1][k] * dx;
            o[3 * 7 + k] = rot[0][k];
            o[4 * 7 + k] = rot[1][k];
            o[5 * 7 + k] = rot[2][k];
        }
    }

    // ---- stage output in pose LDS (reuse), stream out coalesced f4 ----
    __syncthreads();   // all pose LDS reads done
    float* ldsf = reinterpret_cast<float*>(pose_lds);
#pragma unroll
    for (int j = 0; j < 42; ++j) ldsf[tid * 42 + j] = o[j];  // 2688 dwords = 10752B, fits
    __syncthreads();

    // block out region: 64*42 floats = 672 f4 (base = blockIdx*10752B, 16-aligned)
    {
        float4* Ob4 = reinterpret_cast<float4*>(out) + (size_t)blockIdx.x * (BLK * 42 / 4);
        const float4* Lf4 = reinterpret_cast<const float4*>(ldsf);
#pragma unroll
        for (int i = 0; i < 10; ++i) Ob4[tid + i * BLK] = Lf4[tid + i * BLK];
        if (tid < 672 - 10 * BLK)   // 32 lanes
            Ob4[tid + 10 * BLK] = Lf4[tid + 10 * BLK];
    }
}

extern "C" void kernel_launch(void* const* d_in, const int* in_sizes, int n_in,
                              void* d_out, int out_size, void* d_ws, size_t ws_size,
                              hipStream_t stream) {
    const float* com  = (const float*)d_in[0];   // (512,256,3,7)  f32
    const float* pose = (const float*)d_in[1];   // (512,256,4,4,9) f32
    const int*   bm   = (const int*)d_in[2];     // scalar
    float* out = (float*)d_out;                  // (512,256,6,7)  f32

    const int n_items = in_sizes[0] / 21;        // 131072 (divisible by BLK)
    const int grid = n_items / BLK;              // 2048
    canadarm_jacob_kernel<<<grid, BLK, 0, stream>>>(com, pose, bm, out);
}

// Round 7
// 123.812 us; speedup vs baseline: 1.2044x; 1.0044x over previous
//
#include <hip/hip_runtime.h>

// CanadarmJacob: 131072 items. Additive dur model (4 rounds, ±0.2us):
// dur = 94.1(harness resets) + kernel. R2/R4/R6 kernels all ~30-31us at
// ~2TB/s effective vs 6.4TB/s harness-fill rate. Invariant: only 2048
// waves (1 thread/item). R7: BLK=256 / 64 items per block -> 4x waves in
// the memory phases (12 waves/CU vs R6's 5). Wave0 computes; all staged
// via async DMA in, coalesced f4 out. Compute algebra unchanged (verified
// absmax 0.0078).

#define BLK 256
#define ITEMS 64   // items per block; grid = 131072/64 = 2048

typedef const __attribute__((address_space(1))) void GAS;
typedef __attribute__((address_space(3))) void LAS;

__global__ __launch_bounds__(BLK) void canadarm_jacob_kernel(
    const float* __restrict__ com,
    const float* __restrict__ pose,
    const int* __restrict__ bm_ptr,
    float* __restrict__ out)
{
    __shared__ float4 pose_lds[ITEMS * 21];   // 21504 B  (live f4s, compacted)
    __shared__ float4 com_lds[336];           // 5376 B   (64 items * 84B)
    __shared__ float  out_lds[ITEMS * 42];    // 10752 B  -> total 37632 B

    const int tid = threadIdx.x;
    const int item0 = blockIdx.x * ITEMS;

    // ---- async DMA staging (all 4 waves issue) ----
    // pose: 1344 live-f4 slots; slot d = item*21 + (7r+s), src f4 = item*36+9r+off(s)
    // off(s) = s<2 ? s : s+2  (live offs {0,1,4,5,6,7,8} per row)
    {
        const float4* Pb4 = reinterpret_cast<const float4*>(pose) + (size_t)item0 * 36;
#pragma unroll
        for (int i = 0; i < 6; ++i) {
            const int d = i * BLK + tid;                 // 0..1535
            if (d < ITEMS * 21) {                        // i<5 uniform-true; i=5: wave0 only
                const int item = d / 21;
                const int li   = d - item * 21;          // 0..20
                const int r    = li / 7;
                const int q    = li - r * 7;             // 0..6
                const int off  = 9 * r + (q < 2 ? q : q + 2);
                __builtin_amdgcn_global_load_lds(
                    (GAS*)(Pb4 + item * 36 + off),
                    (LAS*)(pose_lds + d), 16, 0, 0);
            }
        }
        // com: identity f4 copy, 336 f4 (64 items * 84B, base 16B-aligned)
        const float4* Cb4 = reinterpret_cast<const float4*>(com + (size_t)item0 * 21);
#pragma unroll
        for (int i = 0; i < 2; ++i) {
            const int c = i * BLK + tid;                 // 0..511
            if (c < 336) {
                __builtin_amdgcn_global_load_lds(
                    (GAS*)(Cb4 + c),
                    (LAS*)(com_lds + c), 16, 0, 0);
            }
        }
    }
    asm volatile("s_waitcnt vmcnt(0)" ::: "memory");
    __syncthreads();

    // ---- compute: wave 0 lanes handle the 64 items ----
    if (tid < ITEMS) {
        const float MASS[7] = {105.98f, 105.98f, 314.98f, 279.2f, 105.98f, 105.98f, 243.66f};
        const float SUMM[7] = {1261.76f, 1155.78f, 1049.80f, 734.82f, 455.62f, 349.64f, 243.66f};
        const float SIX[7] = {79.083f, 66.893f, 54.703f, 39.293f, 29.771f, 21.466f, 9.336f};
        const float SIY[7] = {4144.971f, 4132.781f, 4120.591f, 2025.881f, 59.601f, 56.540f, 44.410f};
        const float SIZ[7] = {4131.1016f, 4128.0406f, 4124.9796f, 2021.7896f, 55.5096f, 47.471f, 44.410f};
        const float TM     = 101505.42f;
        const float INV_TM = 1.0f / 101505.42f;
        const float BCZ    = 6.65f * 243.66f / 100243.66f;

        // extract rot/tr from LDS (f4 stride 21 -> start-bank groups cover all 8)
        const float4* L = &pose_lds[tid * 21];
        float rot[3][7];
        float tr[3][8];
#pragma unroll
        for (int r = 0; r < 3; ++r) {
            const float4 q0 = L[7 * r + 0];
            const float4 q1 = L[7 * r + 1];
            const float4 q4 = L[7 * r + 2];
            const float4 q5 = L[7 * r + 3];
            const float4 q6 = L[7 * r + 4];
            const float4 q7 = L[7 * r + 5];
            const float4 q8 = L[7 * r + 6];
            rot[r][0] = q4.z;
            rot[r][1] = q0.y;
            rot[r][2] = q5.x;
            rot[r][3] = q5.y;
            rot[r][4] = -q5.z;   // ROT_SIGN[4] = -1
            rot[r][5] = q1.y;
            rot[r][6] = q6.x;
            tr[r][0] = q6.w;
            tr[r][1] = q7.x; tr[r][2] = q7.y; tr[r][3] = q7.z; tr[r][4] = q7.w;
            tr[r][5] = q8.x; tr[r][6] = q8.y; tr[r][7] = q8.z;
        }

        const int bm = bm_ptr[0];
        float o[42];

        if (bm) {
            const float* Cf = reinterpret_cast<const float*>(com_lds) + tid * 21;
            float cm[3][7];
#pragma unroll
            for (int r = 0; r < 3; ++r)
#pragma unroll
                for (int i = 0; i < 7; ++i) cm[r][i] = Cf[r * 7 + i];

            float scx = 0.f, scy = 0.f, scz = 0.f;
#pragma unroll
            for (int i = 0; i < 7; ++i) {
                scx += cm[0][i] * MASS[i];
                scy += cm[1][i] * MASS[i];
                scz += cm[2][i] * MASS[i];
            }
            const float vx = scx * INV_TM;
            const float vy = scy * INV_TM;
            const float vz = scz * INV_TM - BCZ;

            float dp[3][7], jt[3][7];
            float hxx = SIX[0], hyy = SIY[0], hzz = SIZ[0];
            float hxy = 0.f, hxz = 0.f, hyz = 0.f;
#pragma unroll
            for (int i = 0; i < 7; ++i) {
                const float x = cm[0][i] - tr[0][i];
                const float y = cm[1][i] - tr[1][i];
                const float z = cm[2][i] - tr[2][i];
                dp[0][i] = x; dp[1][i] = y; dp[2][i] = z;
                jt[0][i] = rot[1][i] * z - rot[2][i] * y;
                jt[1][i] = rot[2][i] * x - rot[0][i] * z;
                jt[2][i] = rot[0][i] * y - rot[1][i] * x;
                const float m = MASS[i];
                hxx += m * (y * y + z * z);
                hyy += m * (x * x + z * z);
                hzz += m * (x * x + y * y);
                hxy -= m * x * y;
                hxz -= m * x * z;
                hyz -= m * y * z;
            }

            float wx[7], wy[7], wz[7];
            wx[6] = MASS[6] * dp[0][6];
            wy[6] = MASS[6] * dp[1][6];
            wz[6] = MASS[6] * dp[2][6];
#pragma unroll
            for (int k = 5; k >= 0; --k) {
                wx[k] = wx[k + 1] + MASS[k] * dp[0][k];
                wy[k] = wy[k + 1] + MASS[k] * dp[1][k];
                wz[k] = wz[k + 1] + MASS[k] * dp[2][k];
            }

            const float vv = vx * vx + vy * vy + vz * vz;
            const float a  = hxx + TM * (vx * vx - vv);
            const float b  = hxy + TM * (vx * vy);
            const float c  = hxz + TM * (vx * vz);
            const float e  = hyy + TM * (vy * vy - vv);
            const float f  = hyz + TM * (vy * vz);
            const float i9 = hzz + TM * (vz * vz - vv);

            const float c11 = e * i9 - f * f;
            const float c12 = c * f - b * i9;
            const float c13 = b * f - e * c;
            const float det = a * c11 + b * c12 + c * c13;
            const float rdet = 1.0f / det;
            const float i00 = c11 * rdet;
            const float i01 = c12 * rdet;
            const float i02 = c13 * rdet;
            const float i11 = (a * i9 - c * c) * rdet;
            const float i12 = (c * b - a * f) * rdet;
            const float i22 = (a * e - b * b) * rdet;

#pragma unroll
            for (int k = 0; k < 7; ++k) {
                const float ux = wx[k] - SUMM[k] * vx;
                const float uy = wy[k] - SUMM[k] * vy;
                const float uz = wz[k] - SUMM[k] * vz;
                const float jx = jt[0][k], jy = jt[1][k], jz = jt[2][k];
                const float htx = SIX[k] * rot[0][k] + uy * jz - uz * jy;
                const float hty = SIY[k] * rot[1][k] + uz * jx - ux * jz;
                const float htz = SIZ[k] * rot[2][k] + ux * jy - uy * jx;
                const float bx = i00 * htx + i01 * hty + i02 * htz;
                const float by = i01 * htx + i11 * hty + i12 * htz;
                const float bz = i02 * htx + i12 * hty + i22 * htz;
                const float s = SUMM[k] * INV_TM;
                o[0 * 7 + k] = -(s * jx + vy * bz - vz * by);
                o[1 * 7 + k] = -(s * jy + vz * bx - vx * bz);
                o[2 * 7 + k] = -(s * jz + vx * by - vy * bx);
                o[3 * 7 + k] = -bx;
                o[4 * 7 + k] = -by;
                o[5 * 7 + k] = -bz;
            }
        } else {
#pragma unroll
            for (int k = 0; k < 7; ++k) {
                const float dx = tr[0][7] - tr[0][k];
                const float dy = tr[1][7] - tr[1][k];
                const float dz = tr[2][7] - tr[2][k];
                o[0 * 7 + k] = rot[1][k] * dz - rot[2][k] * dy;
                o[1 * 7 + k] = rot[2][k] * dx - rot[0][k] * dz;
                o[2 * 7 + k] = rot[0][k] * dy - rot[1][k] * dx;
                o[3 * 7 + k] = rot[0][k];
                o[4 * 7 + k] = rot[1][k];
                o[5 * 7 + k] = rot[2][k];
            }
        }

#pragma unroll
        for (int j = 0; j < 42; ++j) out_lds[tid * 42 + j] = o[j];
    }
    __syncthreads();

    // ---- cooperative coalesced store: 64*42 floats = 672 f4 over 256 threads ----
    {
        float4* Ob4 = reinterpret_cast<float4*>(out) + (size_t)blockIdx.x * (ITEMS * 42 / 4);
        const float4* Lf4 = reinterpret_cast<const float4*>(out_lds);
#pragma unroll
        for (int i = 0; i < 3; ++i) {
            const int s = i * BLK + tid;                 // 0..767
            if (s < ITEMS * 42 / 4) Ob4[s] = Lf4[s];     // i<2 uniform-true; i=2: tid<160
        }
    }
}

extern "C" void kernel_launch(void* const* d_in, const int* in_sizes, int n_in,
                              void* d_out, int out_size, void* d_ws, size_t ws_size,
                              hipStream_t stream) {
    const float* com  = (const float*)d_in[0];   // (512,256,3,7)  f32
    const float* pose = (const float*)d_in[1];   // (512,256,4,4,9) f32
    const int*   bm   = (const int*)d_in[2];     // scalar
    float* out = (float*)d_out;                  // (512,256,6,7)  f32

    const int n_items = in_sizes[0] / 21;        // 131072 (divisible by ITEMS)
    const int grid = n_items / ITEMS;            // 2048
    canadarm_jacob_kernel<<<grid, BLK, 0, stream>>>(com, pose, bm, out);
}